// Round 8
// baseline (213.839 us; speedup 1.0000x reference)
//
#include <hip/hip_runtime.h>
#include <math.h>

#define Bsz  2
#define Ntok 256
#define Ddim 512
#define Hdim 2048
#define Mrows 512

typedef __bf16 bf16_8 __attribute__((ext_vector_type(8)));
typedef __bf16 bf16_4 __attribute__((ext_vector_type(4)));
typedef __bf16 bf16_2 __attribute__((ext_vector_type(2)));
typedef float  f32x4_t __attribute__((ext_vector_type(4)));

// ---------------------------------------------------------------------------
// Prep kernel.
// [0,640):     transpose+cast fp32 [K][N] -> bf16 [N][K], 64x64 tiles
//              (W1v: 256, W1a: 256, Wout: 128 tiles)
// [640,1152):  distance partial sums (j split 4 ways, 8 i-rows per block)
// [1152,1160): bc partials: bcp[kb] = (bm @ Wout)[kb-slice] (+bout on kb==0)
// [1160,1224): zero the fp32 out buffer; first block also zeroes the
//              producer-consumer counter used by kernelAB
// ---------------------------------------------------------------------------
struct PrepPtrs {
    const float* src[3];
    __bf16*      dst[3];
    const float* xv;
    const float* xa;
    float*       pv;       // [4][512] raw sums
    float*       pa;       // [4][512]
    const float* bm[2];
    const float* Wout;     // fp32 [1024][512] native
    const float* bout;
    float*       bc;       // [8][512] partials (plain stores)
    float*       outz;     // out buffer to zero
    int*         cnt;      // producer-consumer counter (zeroed here)
};

__global__ __launch_bounds__(256) void prep_kernel(PrepPtrs p) {
    __shared__ float tile[64][65];
    __shared__ float red[4][8];

    int blk = blockIdx.x;
    int tid = threadIdx.x;

    if (blk < 640) {
        // ---- transpose+cast, 64x64 tile (verified) ----
        const int Ks[3]  = {512, 512, 1024};
        const int Ns[3]  = {2048, 2048, 512};
        const int off[4] = {0, 256, 512, 640};
        int mi = 0;
        while (blk >= off[mi + 1]) ++mi;
        int local = blk - off[mi];
        int shift = (mi < 2) ? 5 : 3;
        int bx = local & ((1 << shift) - 1);
        int by = local >> shift;
        const float* src = p.src[mi];
        __bf16*      dst = p.dst[mi];
        int K = Ks[mi], N = Ns[mi];
        int n0 = bx << 6, k0 = by << 6;

        int klb = tid >> 4, nl = (tid & 15) << 2;
#pragma unroll
        for (int pass = 0; pass < 4; ++pass) {
            int kl = (pass << 4) + klb;
            float4 v = *(const float4*)&src[(size_t)(k0 + kl) * N + n0 + nl];
            tile[kl][nl + 0] = v.x;
            tile[kl][nl + 1] = v.y;
            tile[kl][nl + 2] = v.z;
            tile[kl][nl + 3] = v.w;
        }
        __syncthreads();
        int nl2 = tid >> 2, kb = (tid & 3) << 2;
#pragma unroll
        for (int pass = 0; pass < 4; ++pass) {
            int kl2 = (pass << 4) + kb;
            bf16_4 o;
#pragma unroll
            for (int i = 0; i < 4; ++i) o[i] = (__bf16)tile[kl2 + i][nl2];
            *(bf16_4*)&dst[(size_t)(n0 + nl2) * K + k0 + kl2] = o;
        }
    } else if (blk < 1152) {
        // ---- distance partials, 8 i-rows per block ----
        int bx   = blk - 640;
        int jc   = bx & 3;
        int g    = bx >> 2;          // 0..127
        int role = g >> 6;
        int b    = (g >> 5) & 1;
        int i0   = (g & 31) << 3;    // 8-row groups
        const float* Q    = role ? p.xa : p.xv;
        const float* S    = role ? p.xv : p.xa;
        float*       outp = role ? p.pa : p.pv;

        int d0 = tid << 1;
        const float* Qb = Q + ((size_t)b * Ntok + i0) * Ddim + d0;
        const float* Sb = S + ((size_t)b * Ntok + (jc << 6)) * Ddim + d0;

        float2 q[8];
#pragma unroll
        for (int r = 0; r < 8; ++r) q[r] = *(const float2*)(Qb + r * Ddim);

        float acc[8] = {0.f, 0.f, 0.f, 0.f, 0.f, 0.f, 0.f, 0.f};
#pragma unroll 2
        for (int j = 0; j < 64; ++j) {
            float2 s = *(const float2*)(Sb + (size_t)j * Ddim);
#pragma unroll
            for (int r = 0; r < 8; ++r)
                acc[r] += fabsf(q[r].x - s.x) + fabsf(q[r].y - s.y);
        }
        int lane = tid & 63, wv = tid >> 6;
#pragma unroll
        for (int r = 0; r < 8; ++r) {
            float v = acc[r];
#pragma unroll
            for (int off2 = 32; off2; off2 >>= 1) v += __shfl_down(v, off2);
            if (lane == 0) red[wv][r] = v;
        }
        __syncthreads();
        if (tid < 8) {
            float v = red[0][tid] + red[1][tid] + red[2][tid] + red[3][tid];
            outp[jc * Mrows + b * Ntok + i0 + tid] = v;
        }
    } else if (blk < 1160) {
        // ---- bc GEMV partials: 8 blocks x 128 k-rows, plain stores ----
        int kb = blk - 1152;
        float a0 = 0.f, a1 = 0.f, a2 = 0.f, a3 = 0.f;
#pragma unroll 4
        for (int kk = 0; kk < 128; kk += 2) {
            int k0 = (kb << 7) + kk, k1 = k0 + 1;
            float bk0 = (k0 < 512) ? p.bm[0][k0] : p.bm[1][k0 - 512];
            float bk1 = (k1 < 512) ? p.bm[0][k1] : p.bm[1][k1 - 512];
            a0 += bk0 * p.Wout[(size_t)k0 * Ddim + tid];
            a1 += bk0 * p.Wout[(size_t)k0 * Ddim + tid + 256];
            a2 += bk1 * p.Wout[(size_t)k1 * Ddim + tid];
            a3 += bk1 * p.Wout[(size_t)k1 * Ddim + tid + 256];
        }
        if (kb == 0) { a0 += p.bout[tid]; a1 += p.bout[tid + 256]; }
        p.bc[(kb << 9) + tid]       = a0 + a2;
        p.bc[(kb << 9) + tid + 256] = a1 + a3;
    } else {
        // ---- zero out buffer: 64 blocks x 16 KB; block 1160 zeroes cnt ----
        int ib = blk - 1160;
        if (ib == 0 && tid == 0) *p.cnt = 0;
        float4 z4 = {0.f, 0.f, 0.f, 0.f};
        float4* o = (float4*)p.outz + (size_t)ib * 1024 + tid;
#pragma unroll
        for (int pass = 0; pass < 4; ++pass) o[pass * 256] = z4;
    }
}

// ---------------------------------------------------------------------------
// One 64x64 GEMM tile, 2-deep pipelined ping-pong LDS, BK=32 (verified).
// AMODE: 0 = bf16 A ; 1 = fp32 A scaled by mean-dist ; 3 = bf16 A scaled
// BFP32: 0 = bf16 B ; 1 = fp32 B (cast to bf16 at staging)
// OUTM : 1 = bf16 store ; 2 = fp32 atomicAdd
// addBias: 0 = none ; 1 = bias[colg] ; 2 = sum of 8 partials bias[k*512+colg]
// ---------------------------------------------------------------------------
template <int GELU, int AMODE, int BFP32, int OUTM>
__device__ void gemm_tile(__bf16 (&As)[2][64][40], __bf16 (&Bs)[2][64][40],
                          const void* Aa, int lda, const void* Bv, int ldb,
                          const float* bias, const float* scale4,
                          void* C, int ldc, int Kdim,
                          int m0, int n0, int addBias) {
    const int tid = threadIdx.x;
    const int row = tid >> 2;        // 0..63
    const int kc  = (tid & 3) << 3;  // 0,8,16,24

    const __bf16* Bb  = (const __bf16*)Bv + (size_t)(n0 + row) * ldb + kc;
    const float*  Bf  = (const float*)Bv + (size_t)(n0 + row) * ldb + kc;
    const float*  Af  = (const float*)Aa + (size_t)(m0 + row) * lda + kc;
    const __bf16* Ab  = (const __bf16*)Aa + (size_t)(m0 + row) * lda + kc;
    float s = 1.0f;
    if (AMODE == 1 || AMODE == 3) {
        int m = m0 + row;
        s = (scale4[m] + scale4[Mrows + m] + scale4[2 * Mrows + m] +
             scale4[3 * Mrows + m]) * (1.0f / 256.0f);
    }

    const int wave = tid >> 6, lane = tid & 63;
    const int moff = (wave >> 1) << 5, noff = (wave & 1) << 5;
    const int lrow = lane & 15, quad = lane >> 4;

    struct Stage {
        float4 aF0, aF1, bF0, bF1;
        bf16_8 a8, b8;
    };
    Stage sR, sN;

    auto loadStage = [&](int kt, Stage& st) {
        if (BFP32) {
            st.bF0 = *(const float4*)(Bf + kt);
            st.bF1 = *(const float4*)(Bf + kt + 4);
        } else {
            st.b8 = *(const bf16_8*)(Bb + kt);
        }
        if (AMODE == 1) {
            st.aF0 = *(const float4*)(Af + kt);
            st.aF1 = *(const float4*)(Af + kt + 4);
        } else {
            st.a8 = *(const bf16_8*)(Ab + kt);
        }
    };
    auto storeStage = [&](int buf, const Stage& st) {
        bf16_8 a8, b8;
        if (AMODE == 1) {
            a8[0] = (__bf16)(st.aF0.x * s); a8[1] = (__bf16)(st.aF0.y * s);
            a8[2] = (__bf16)(st.aF0.z * s); a8[3] = (__bf16)(st.aF0.w * s);
            a8[4] = (__bf16)(st.aF1.x * s); a8[5] = (__bf16)(st.aF1.y * s);
            a8[6] = (__bf16)(st.aF1.z * s); a8[7] = (__bf16)(st.aF1.w * s);
        } else if (AMODE == 3) {
#pragma unroll
            for (int i = 0; i < 8; ++i)
                a8[i] = (__bf16)((float)st.a8[i] * s);
        } else {
            a8 = st.a8;
        }
        if (BFP32) {
            b8[0] = (__bf16)st.bF0.x; b8[1] = (__bf16)st.bF0.y;
            b8[2] = (__bf16)st.bF0.z; b8[3] = (__bf16)st.bF0.w;
            b8[4] = (__bf16)st.bF1.x; b8[5] = (__bf16)st.bF1.y;
            b8[6] = (__bf16)st.bF1.z; b8[7] = (__bf16)st.bF1.w;
        } else {
            b8 = st.b8;
        }
        *(bf16_8*)&As[buf][row][kc] = a8;
        *(bf16_8*)&Bs[buf][row][kc] = b8;
    };

    f32x4_t acc00 = {0.f, 0.f, 0.f, 0.f};
    f32x4_t acc01 = {0.f, 0.f, 0.f, 0.f};
    f32x4_t acc10 = {0.f, 0.f, 0.f, 0.f};
    f32x4_t acc11 = {0.f, 0.f, 0.f, 0.f};

    const int nIter = Kdim >> 5;

    loadStage(0, sR);
    storeStage(0, sR);
    if (nIter > 1) loadStage(32, sR);
    __syncthreads();

    for (int it = 0; it < nIter; ++it) {
        const int cur = it & 1;
        bf16_8 a0 = *(const bf16_8*)&As[cur][moff + lrow][quad << 3];
        bf16_8 a1 = *(const bf16_8*)&As[cur][moff + 16 + lrow][quad << 3];
        bf16_8 b0 = *(const bf16_8*)&Bs[cur][noff + lrow][quad << 3];
        bf16_8 b1 = *(const bf16_8*)&Bs[cur][noff + 16 + lrow][quad << 3];
        if (it + 2 < nIter) loadStage((it + 2) << 5, sN);
        acc00 = __builtin_amdgcn_mfma_f32_16x16x32_bf16(a0, b0, acc00, 0, 0, 0);
        acc01 = __builtin_amdgcn_mfma_f32_16x16x32_bf16(a0, b1, acc01, 0, 0, 0);
        acc10 = __builtin_amdgcn_mfma_f32_16x16x32_bf16(a1, b0, acc10, 0, 0, 0);
        acc11 = __builtin_amdgcn_mfma_f32_16x16x32_bf16(a1, b1, acc11, 0, 0, 0);
        if (it + 1 < nIter) {
            storeStage(cur ^ 1, sR);
            sR = sN;
            __syncthreads();
        }
    }

    f32x4_t accs[2][2] = {{acc00, acc01}, {acc10, acc11}};
#pragma unroll
    for (int ti = 0; ti < 2; ++ti) {
#pragma unroll
        for (int tj = 0; tj < 2; ++tj) {
            int colg = n0 + noff + (tj << 4) + lrow;
            float bv = 0.0f;
            if (addBias == 1) {
                bv = bias[colg];
            } else if (addBias == 2) {
#pragma unroll
                for (int k = 0; k < 8; ++k) bv += bias[(k << 9) + colg];
            }
#pragma unroll
            for (int r = 0; r < 4; ++r) {
                int rowg = m0 + moff + (ti << 4) + (quad << 2) + r;
                float v = accs[ti][tj][r] + bv;
                if (GELU) v = 0.5f * v * (1.0f + erff(v * 0.70710678118654752f));
                if (OUTM == 1)
                    ((__bf16*)C)[(size_t)rowg * ldc + colg] = (__bf16)v;
                else
                    atomicAdd((float*)C + (size_t)rowg * ldc + colg, v);
            }
        }
    }
}

// ---------------------------------------------------------------------------
// kernelAB: fused kernelA + kernelB in one dispatch, 1280 blocks.
// All 1280 blocks are co-resident (20 KB LDS -> 8 blocks/CU -> 2048 slots),
// so the consumer spin-wait cannot deadlock under any dispatch order.
//  [0,512):     gemm1  g1[z] = gelu(diag(d) * x[z] @ W1[z] + b1[z]),
//               fp32 A read natively (AMODE=1, scale at staging)
//  [512,1024):  WcT[z] = WToutslice(z) @ Wm[z]
//  each producer block: syncthreads (drains stores) + agent-scope
//  release fetch_add on cnt.
//  [1024,1280): kernelB tiles; thread 0 spins on acquire load of cnt
//  until 1024, then out = sum_z g1[z] @ WcT[z]^T + bc (split-K4,
//  atomicAdd into prep-zeroed out; kz==0 adds summed bc partials).
// ---------------------------------------------------------------------------
struct ABPtrs {
    const float*  x[2];      // fp32 x_v, x_a native [512][512]
    const __bf16* WT1[2];    // [2048][512]
    const float*  b1[2];
    const float*  pd[2];     // [4][512]
    __bf16*       g1[2];     // [512][2048]
    const __bf16* WTout;     // [512][1024]
    const float*  Wm[2];     // fp32 [2048][512] native
    __bf16*       WcT[2];    // [512][2048]
    const float*  bc;        // [8][512] partials
    float*        out;       // [512][512] fp32, zeroed by prep
    int*          cnt;       // zeroed by prep
};

__global__ __launch_bounds__(256) void kernelAB(ABPtrs p) {
    __shared__ __align__(16) __bf16 As[2][64][40];
    __shared__ __align__(16) __bf16 Bs[2][64][40];
    int blk = blockIdx.x;
    int tid = threadIdx.x;
    if (blk < 1024) {
        if (blk < 512) {
            int z = blk >> 8, t = blk & 255;
            int mt = t >> 5, nt = t & 31;
            gemm_tile<1, 1, 0, 1>(As, Bs, p.x[z], Ddim, p.WT1[z], Ddim,
                                  p.b1[z], p.pd[z], p.g1[z], Hdim, Ddim,
                                  mt << 6, nt << 6, 1);
        } else {
            int b2 = blk - 512;
            int z = b2 >> 8, t = b2 & 255;
            int mt = t >> 5, nt = t & 31;
            gemm_tile<0, 0, 1, 1>(As, Bs, p.WTout + z * 512, 2 * Ddim,
                                  p.Wm[z], Ddim, nullptr, nullptr,
                                  p.WcT[z], Hdim, Ddim, mt << 6, nt << 6, 0);
        }
        // signal: all stores of this block drained by syncthreads' waitcnt
        __syncthreads();
        if (tid == 0)
            __hip_atomic_fetch_add(p.cnt, 1, __ATOMIC_RELEASE,
                                   __HIP_MEMORY_SCOPE_AGENT);
    } else {
        if (tid == 0) {
            while (__hip_atomic_load(p.cnt, __ATOMIC_ACQUIRE,
                                     __HIP_MEMORY_SCOPE_AGENT) < 1024)
                __builtin_amdgcn_s_sleep(16);
        }
        __syncthreads();
        int bk = blk - 1024;
        int nt = bk & 7, mt = (bk >> 3) & 7, kz = bk >> 6;
        int z = kz >> 1, koff = (kz & 1) << 10;
        gemm_tile<0, 0, 0, 2>(As, Bs, p.g1[z] + koff, Hdim,
                              p.WcT[z] + koff, Hdim,
                              p.bc, nullptr, p.out, Ddim, 1024,
                              mt << 6, nt << 6, kz == 0 ? 2 : 0);
    }
}

extern "C" void kernel_launch(void* const* d_in, const int* in_sizes, int n_in,
                              void* d_out, int out_size, void* d_ws, size_t ws_size,
                              hipStream_t stream) {
    const float* x_v  = (const float*)d_in[0];
    const float* x_a  = (const float*)d_in[1];
    const float* W1v  = (const float*)d_in[2];
    const float* b1v  = (const float*)d_in[3];
    const float* W1a  = (const float*)d_in[4];
    const float* b1a  = (const float*)d_in[5];
    const float* Wmv  = (const float*)d_in[6];
    const float* bmv  = (const float*)d_in[7];
    const float* Wma  = (const float*)d_in[8];
    const float* bma  = (const float*)d_in[9];
    const float* Wout = (const float*)d_in[10];
    const float* bout = (const float*)d_in[11];
    float* out = (float*)d_out;

    char* w = (char*)d_ws;
    auto alloc = [&](size_t bytes) {
        char* r = w;
        w += (bytes + 255) & ~(size_t)255;
        return (void*)r;
    };
    float*    pv    = (float*)alloc(4 * Mrows * 4);
    float*    pa    = (float*)alloc(4 * Mrows * 4);
    float*    bc    = (float*)alloc(8 * Ddim * 4);                  // [8][512]
    int*      cnt   = (int*)alloc(256);
    __bf16*   WT1v  = (__bf16*)alloc((size_t)Hdim * Ddim * 2);      // [2048][512]
    __bf16*   WT1a  = (__bf16*)alloc((size_t)Hdim * Ddim * 2);
    __bf16*   WTout = (__bf16*)alloc((size_t)Ddim * 2 * Ddim * 2);  // [512][1024]
    __bf16*   WcTv  = (__bf16*)alloc((size_t)Ddim * Hdim * 2);      // [512][2048]
    __bf16*   WcTa  = (__bf16*)alloc((size_t)Ddim * Hdim * 2);
    __bf16*   g1v   = (__bf16*)alloc((size_t)Mrows * Hdim * 2);
    __bf16*   g1a   = (__bf16*)alloc((size_t)Mrows * Hdim * 2);

    // 1) prep: transposes + dist partials + bc partials + out/cnt zero
    PrepPtrs pp;
    pp.src[0] = W1v;  pp.dst[0] = WT1v;
    pp.src[1] = W1a;  pp.dst[1] = WT1a;
    pp.src[2] = Wout; pp.dst[2] = WTout;
    pp.xv = x_v; pp.xa = x_a;
    pp.pv = pv; pp.pa = pa;
    pp.bm[0] = bmv; pp.bm[1] = bma;
    pp.Wout = Wout; pp.bout = bout;
    pp.bc = bc;
    pp.outz = out;
    pp.cnt = cnt;
    prep_kernel<<<dim3(1224), dim3(256), 0, stream>>>(pp);

    // 2) kernelAB: gemm1 + WcT producers, then kernelB consumers
    ABPtrs ab;
    ab.x[0] = x_v; ab.x[1] = x_a;
    ab.WT1[0] = WT1v; ab.WT1[1] = WT1a;
    ab.b1[0] = b1v; ab.b1[1] = b1a;
    ab.pd[0] = pv; ab.pd[1] = pa;
    ab.g1[0] = g1v; ab.g1[1] = g1a;
    ab.WTout = WTout;
    ab.Wm[0] = Wmv; ab.Wm[1] = Wma;
    ab.WcT[0] = WcTv; ab.WcT[1] = WcTa;
    ab.bc = bc; ab.out = out;
    ab.cnt = cnt;
    kernelAB<<<dim3(1280), dim3(256), 0, stream>>>(ab);
}

// Round 9
// 127.085 us; speedup vs baseline: 1.6826x; 1.6826x over previous
//
#include <hip/hip_runtime.h>
#include <math.h>

#define Bsz  2
#define Ntok 256
#define Ddim 512
#define Hdim 2048
#define Mrows 512

typedef __bf16 bf16_8 __attribute__((ext_vector_type(8)));
typedef __bf16 bf16_4 __attribute__((ext_vector_type(4)));
typedef __bf16 bf16_2 __attribute__((ext_vector_type(2)));
typedef float  f32x4_t __attribute__((ext_vector_type(4)));

// ---------------------------------------------------------------------------
// Prep kernel.
// [0,640):     transpose+cast fp32 [K][N] -> bf16 [N][K], 64x64 tiles
//              (W1v: 256, W1a: 256, Wout: 128 tiles)
// [640,1664):  distance partial sums (j split 4 ways); jc==0 blocks also
//              write bf16 copies of their x rows (for gemm1's A fetch)
// [1664,1672): bc partials: bcp[kb] = (bm @ Wout)[kb-slice] (+bout on kb==0)
//              plain stores, summed in kernelB's bias path (no memset needed)
// [1672,1736): zero the fp32 out buffer (replaces hipMemsetAsync dispatch)
// ---------------------------------------------------------------------------
struct PrepPtrs {
    const float* src[3];
    __bf16*      dst[3];
    const float* xv;
    const float* xa;
    __bf16*      xbf[2];   // bf16 copies of x_v, x_a  [512][512]
    float*       pv;       // [4][512] raw sums
    float*       pa;       // [4][512]
    const float* bm[2];
    const float* Wout;     // fp32 [1024][512] native
    const float* bout;
    float*       bc;       // [8][512] partials (plain stores)
    float*       outz;     // out buffer to zero
};

__global__ __launch_bounds__(256) void prep_kernel(PrepPtrs p) {
    __shared__ float tile[64][65];
    __shared__ float red[4][4];

    int blk = blockIdx.x;
    int tid = threadIdx.x;

    if (blk < 640) {
        // ---- transpose+cast, 64x64 tile (verified) ----
        const int Ks[3]  = {512, 512, 1024};
        const int Ns[3]  = {2048, 2048, 512};
        const int off[4] = {0, 256, 512, 640};
        int mi = 0;
        while (blk >= off[mi + 1]) ++mi;
        int local = blk - off[mi];
        int shift = (mi < 2) ? 5 : 3;
        int bx = local & ((1 << shift) - 1);
        int by = local >> shift;
        const float* src = p.src[mi];
        __bf16*      dst = p.dst[mi];
        int K = Ks[mi], N = Ns[mi];
        int n0 = bx << 6, k0 = by << 6;

        int klb = tid >> 4, nl = (tid & 15) << 2;
#pragma unroll
        for (int pass = 0; pass < 4; ++pass) {
            int kl = (pass << 4) + klb;
            float4 v = *(const float4*)&src[(size_t)(k0 + kl) * N + n0 + nl];
            tile[kl][nl + 0] = v.x;
            tile[kl][nl + 1] = v.y;
            tile[kl][nl + 2] = v.z;
            tile[kl][nl + 3] = v.w;
        }
        __syncthreads();
        int nl2 = tid >> 2, kb = (tid & 3) << 2;
#pragma unroll
        for (int pass = 0; pass < 4; ++pass) {
            int kl2 = (pass << 4) + kb;
            bf16_4 o;
#pragma unroll
            for (int i = 0; i < 4; ++i) o[i] = (__bf16)tile[kl2 + i][nl2];
            *(bf16_4*)&dst[(size_t)(n0 + nl2) * K + k0 + kl2] = o;
        }
    } else if (blk < 1664) {
        // ---- distance partials (verified) + x bf16 cast on jc==0 ----
        int bx   = blk - 640;
        int jc   = bx & 3;
        int g    = bx >> 2;
        int role = g >> 7;
        int b    = (g >> 6) & 1;
        int i0   = (g & 63) << 2;
        const float* Q    = role ? p.xa : p.xv;
        const float* S    = role ? p.xv : p.xa;
        float*       outp = role ? p.pa : p.pv;

        int d0 = tid << 1;
        const float* Qb = Q + ((size_t)b * Ntok + i0) * Ddim + d0;
        const float* Sb = S + ((size_t)b * Ntok + (jc << 6)) * Ddim + d0;

        float2 q[4];
#pragma unroll
        for (int r = 0; r < 4; ++r) q[r] = *(const float2*)(Qb + r * Ddim);

        if (jc == 0) {
            __bf16* xb = p.xbf[role];
#pragma unroll
            for (int r = 0; r < 4; ++r) {
                bf16_2 o;
                o[0] = (__bf16)q[r].x;
                o[1] = (__bf16)q[r].y;
                *(bf16_2*)&xb[((size_t)b * Ntok + i0 + r) * Ddim + d0] = o;
            }
        }

        float acc[4] = {0.f, 0.f, 0.f, 0.f};
#pragma unroll 4
        for (int j = 0; j < 64; ++j) {
            float2 s = *(const float2*)(Sb + (size_t)j * Ddim);
#pragma unroll
            for (int r = 0; r < 4; ++r)
                acc[r] += fabsf(q[r].x - s.x) + fabsf(q[r].y - s.y);
        }
        int lane = tid & 63, wv = tid >> 6;
#pragma unroll
        for (int r = 0; r < 4; ++r) {
            float v = acc[r];
#pragma unroll
            for (int off2 = 32; off2; off2 >>= 1) v += __shfl_down(v, off2);
            if (lane == 0) red[wv][r] = v;
        }
        __syncthreads();
        if (tid < 4) {
            float v = red[0][tid] + red[1][tid] + red[2][tid] + red[3][tid];
            outp[jc * Mrows + b * Ntok + i0 + tid] = v;
        }
    } else if (blk < 1672) {
        // ---- bc GEMV partials: 8 blocks x 128 k-rows, plain stores ----
        int kb = blk - 1664;
        float a0 = 0.f, a1 = 0.f, a2 = 0.f, a3 = 0.f;
#pragma unroll 4
        for (int kk = 0; kk < 128; kk += 2) {
            int k0 = (kb << 7) + kk, k1 = k0 + 1;
            float bk0 = (k0 < 512) ? p.bm[0][k0] : p.bm[1][k0 - 512];
            float bk1 = (k1 < 512) ? p.bm[0][k1] : p.bm[1][k1 - 512];
            a0 += bk0 * p.Wout[(size_t)k0 * Ddim + tid];
            a1 += bk0 * p.Wout[(size_t)k0 * Ddim + tid + 256];
            a2 += bk1 * p.Wout[(size_t)k1 * Ddim + tid];
            a3 += bk1 * p.Wout[(size_t)k1 * Ddim + tid + 256];
        }
        if (kb == 0) { a0 += p.bout[tid]; a1 += p.bout[tid + 256]; }
        p.bc[(kb << 9) + tid]       = a0 + a2;
        p.bc[(kb << 9) + tid + 256] = a1 + a3;
    } else {
        // ---- zero out buffer: 64 blocks x 16 KB ----
        int ib = blk - 1672;
        float4 z4 = {0.f, 0.f, 0.f, 0.f};
        float4* o = (float4*)p.outz + (size_t)ib * 1024 + tid;
#pragma unroll
        for (int pass = 0; pass < 4; ++pass) o[pass * 256] = z4;
    }
}

// ---------------------------------------------------------------------------
// One 64x64 GEMM tile, 2-deep pipelined ping-pong LDS, BK=32 (verified).
// AMODE: 0 = bf16 A ; 1 = fp32 A scaled by mean-dist ; 3 = bf16 A scaled
// BFP32: 0 = bf16 B ; 1 = fp32 B (cast to bf16 at staging)
// OUTM : 1 = bf16 store ; 2 = fp32 atomicAdd
// addBias: 0 = none ; 1 = bias[colg] ; 2 = sum of 8 partials bias[k*512+colg]
// ---------------------------------------------------------------------------
template <int GELU, int AMODE, int BFP32, int OUTM>
__device__ void gemm_tile(__bf16 (&As)[2][64][40], __bf16 (&Bs)[2][64][40],
                          const void* Aa, int lda, const void* Bv, int ldb,
                          const float* bias, const float* scale4,
                          void* C, int ldc, int Kdim,
                          int m0, int n0, int addBias) {
    const int tid = threadIdx.x;
    const int row = tid >> 2;        // 0..63
    const int kc  = (tid & 3) << 3;  // 0,8,16,24

    const __bf16* Bb  = (const __bf16*)Bv + (size_t)(n0 + row) * ldb + kc;
    const float*  Bf  = (const float*)Bv + (size_t)(n0 + row) * ldb + kc;
    const float*  Af  = (const float*)Aa + (size_t)(m0 + row) * lda + kc;
    const __bf16* Ab  = (const __bf16*)Aa + (size_t)(m0 + row) * lda + kc;
    float s = 1.0f;
    if (AMODE == 1 || AMODE == 3) {
        int m = m0 + row;
        s = (scale4[m] + scale4[Mrows + m] + scale4[2 * Mrows + m] +
             scale4[3 * Mrows + m]) * (1.0f / 256.0f);
    }

    const int wave = tid >> 6, lane = tid & 63;
    const int moff = (wave >> 1) << 5, noff = (wave & 1) << 5;
    const int lrow = lane & 15, quad = lane >> 4;

    struct Stage {
        float4 aF0, aF1, bF0, bF1;
        bf16_8 a8, b8;
    };
    Stage sR, sN;

    auto loadStage = [&](int kt, Stage& st) {
        if (BFP32) {
            st.bF0 = *(const float4*)(Bf + kt);
            st.bF1 = *(const float4*)(Bf + kt + 4);
        } else {
            st.b8 = *(const bf16_8*)(Bb + kt);
        }
        if (AMODE == 1) {
            st.aF0 = *(const float4*)(Af + kt);
            st.aF1 = *(const float4*)(Af + kt + 4);
        } else {
            st.a8 = *(const bf16_8*)(Ab + kt);
        }
    };
    auto storeStage = [&](int buf, const Stage& st) {
        bf16_8 a8, b8;
        if (AMODE == 1) {
            a8[0] = (__bf16)(st.aF0.x * s); a8[1] = (__bf16)(st.aF0.y * s);
            a8[2] = (__bf16)(st.aF0.z * s); a8[3] = (__bf16)(st.aF0.w * s);
            a8[4] = (__bf16)(st.aF1.x * s); a8[5] = (__bf16)(st.aF1.y * s);
            a8[6] = (__bf16)(st.aF1.z * s); a8[7] = (__bf16)(st.aF1.w * s);
        } else if (AMODE == 3) {
#pragma unroll
            for (int i = 0; i < 8; ++i)
                a8[i] = (__bf16)((float)st.a8[i] * s);
        } else {
            a8 = st.a8;
        }
        if (BFP32) {
            b8[0] = (__bf16)st.bF0.x; b8[1] = (__bf16)st.bF0.y;
            b8[2] = (__bf16)st.bF0.z; b8[3] = (__bf16)st.bF0.w;
            b8[4] = (__bf16)st.bF1.x; b8[5] = (__bf16)st.bF1.y;
            b8[6] = (__bf16)st.bF1.z; b8[7] = (__bf16)st.bF1.w;
        } else {
            b8 = st.b8;
        }
        *(bf16_8*)&As[buf][row][kc] = a8;
        *(bf16_8*)&Bs[buf][row][kc] = b8;
    };

    f32x4_t acc00 = {0.f, 0.f, 0.f, 0.f};
    f32x4_t acc01 = {0.f, 0.f, 0.f, 0.f};
    f32x4_t acc10 = {0.f, 0.f, 0.f, 0.f};
    f32x4_t acc11 = {0.f, 0.f, 0.f, 0.f};

    const int nIter = Kdim >> 5;

    loadStage(0, sR);
    storeStage(0, sR);
    if (nIter > 1) loadStage(32, sR);
    __syncthreads();

    for (int it = 0; it < nIter; ++it) {
        const int cur = it & 1;
        bf16_8 a0 = *(const bf16_8*)&As[cur][moff + lrow][quad << 3];
        bf16_8 a1 = *(const bf16_8*)&As[cur][moff + 16 + lrow][quad << 3];
        bf16_8 b0 = *(const bf16_8*)&Bs[cur][noff + lrow][quad << 3];
        bf16_8 b1 = *(const bf16_8*)&Bs[cur][noff + 16 + lrow][quad << 3];
        if (it + 2 < nIter) loadStage((it + 2) << 5, sN);
        acc00 = __builtin_amdgcn_mfma_f32_16x16x32_bf16(a0, b0, acc00, 0, 0, 0);
        acc01 = __builtin_amdgcn_mfma_f32_16x16x32_bf16(a0, b1, acc01, 0, 0, 0);
        acc10 = __builtin_amdgcn_mfma_f32_16x16x32_bf16(a1, b0, acc10, 0, 0, 0);
        acc11 = __builtin_amdgcn_mfma_f32_16x16x32_bf16(a1, b1, acc11, 0, 0, 0);
        if (it + 1 < nIter) {
            storeStage(cur ^ 1, sR);
            sR = sN;
            __syncthreads();
        }
    }

    f32x4_t accs[2][2] = {{acc00, acc01}, {acc10, acc11}};
#pragma unroll
    for (int ti = 0; ti < 2; ++ti) {
#pragma unroll
        for (int tj = 0; tj < 2; ++tj) {
            int colg = n0 + noff + (tj << 4) + lrow;
            float bv = 0.0f;
            if (addBias == 1) {
                bv = bias[colg];
            } else if (addBias == 2) {
#pragma unroll
                for (int k = 0; k < 8; ++k) bv += bias[(k << 9) + colg];
            }
#pragma unroll
            for (int r = 0; r < 4; ++r) {
                int rowg = m0 + moff + (ti << 4) + (quad << 2) + r;
                float v = accs[ti][tj][r] + bv;
                if (GELU) v = 0.5f * v * (1.0f + erff(v * 0.70710678118654752f));
                if (OUTM == 1)
                    ((__bf16*)C)[(size_t)rowg * ldc + colg] = (__bf16)v;
                else
                    atomicAdd((float*)C + (size_t)rowg * ldc + colg, v);
            }
        }
    }
}

// ---------------------------------------------------------------------------
// kernelA: two independent GEMM jobs, 1024 blocks = 4/CU:
//  [0,512):    gemm1  g1[z] = gelu(diag(d)*xbf[z] @ W1[z] + b1[z])
//  [512,1024): WcT[z] = WToutslice(z) @ Wm[z]  (B-layout for kernelB)
// ---------------------------------------------------------------------------
struct APtrs {
    const __bf16* xbf[2];    // [512][512] bf16 (from prep)
    const __bf16* WT1[2];    // [2048][512]
    const float*  b1[2];
    const float*  pd[2];     // [4][512]
    __bf16*       g1[2];     // [512][2048]
    const __bf16* WTout;     // [512][1024]
    const float*  Wm[2];     // fp32 [2048][512] native
    __bf16*       WcT[2];    // [512][2048]
};

__global__ __launch_bounds__(256) void kernelA(APtrs p) {
    __shared__ __align__(16) __bf16 As[2][64][40];
    __shared__ __align__(16) __bf16 Bs[2][64][40];
    int blk = blockIdx.x;
    if (blk < 512) {
        int z = blk >> 8, t = blk & 255;
        int mt = t >> 5, nt = t & 31;
        gemm_tile<1, 3, 0, 1>(As, Bs, p.xbf[z], Ddim, p.WT1[z], Ddim,
                              p.b1[z], p.pd[z], p.g1[z], Hdim, Ddim,
                              mt << 6, nt << 6, 1);
    } else {
        int b2 = blk - 512;
        int z = b2 >> 8, t = b2 & 255;
        int mt = t >> 5, nt = t & 31;
        gemm_tile<0, 0, 1, 1>(As, Bs, p.WTout + z * 512, 2 * Ddim,
                              p.Wm[z], Ddim, nullptr, nullptr,
                              p.WcT[z], Hdim, Ddim, mt << 6, nt << 6, 0);
    }
}

// ---------------------------------------------------------------------------
// kernelB: out = sum_z g1[z] @ WcT[z]^T + bc.  split-K8: 8n x 8m x 8kz = 512
// blocks x 16 iters; fp32 atomicAdd into out zeroed by prep.
// kz==0 blocks add the bias as the sum of the 8 bc partials.
// ---------------------------------------------------------------------------
struct BPtrs {
    const __bf16* g1[2];     // [512][2048]
    const __bf16* WcT[2];    // [512][2048]
    const float*  bc;        // [8][512] partials
    float*        out;       // [512][512] fp32, zeroed by prep
};

__global__ __launch_bounds__(256) void kernelB(BPtrs p) {
    __shared__ __align__(16) __bf16 As[2][64][40];
    __shared__ __align__(16) __bf16 Bs[2][64][40];
    int nt = blockIdx.x & 7, mt = (blockIdx.x >> 3) & 7, kz = blockIdx.x >> 6;
    int z = kz >> 2, koff = (kz & 3) << 9;
    gemm_tile<0, 0, 0, 2>(As, Bs, p.g1[z] + koff, Hdim, p.WcT[z] + koff, Hdim,
                          p.bc, nullptr, p.out, Ddim, Ddim,
                          mt << 6, nt << 6, kz == 0 ? 2 : 0);
}

extern "C" void kernel_launch(void* const* d_in, const int* in_sizes, int n_in,
                              void* d_out, int out_size, void* d_ws, size_t ws_size,
                              hipStream_t stream) {
    const float* x_v  = (const float*)d_in[0];
    const float* x_a  = (const float*)d_in[1];
    const float* W1v  = (const float*)d_in[2];
    const float* b1v  = (const float*)d_in[3];
    const float* W1a  = (const float*)d_in[4];
    const float* b1a  = (const float*)d_in[5];
    const float* Wmv  = (const float*)d_in[6];
    const float* bmv  = (const float*)d_in[7];
    const float* Wma  = (const float*)d_in[8];
    const float* bma  = (const float*)d_in[9];
    const float* Wout = (const float*)d_in[10];
    const float* bout = (const float*)d_in[11];
    float* out = (float*)d_out;

    char* w = (char*)d_ws;
    auto alloc = [&](size_t bytes) {
        char* r = w;
        w += (bytes + 255) & ~(size_t)255;
        return (void*)r;
    };
    float*    pv    = (float*)alloc(4 * Mrows * 4);
    float*    pa    = (float*)alloc(4 * Mrows * 4);
    float*    bc    = (float*)alloc(8 * Ddim * 4);                  // [8][512]
    __bf16*   xbfv  = (__bf16*)alloc((size_t)Mrows * Ddim * 2);     // [512][512]
    __bf16*   xbfa  = (__bf16*)alloc((size_t)Mrows * Ddim * 2);
    __bf16*   WT1v  = (__bf16*)alloc((size_t)Hdim * Ddim * 2);      // [2048][512]
    __bf16*   WT1a  = (__bf16*)alloc((size_t)Hdim * Ddim * 2);
    __bf16*   WTout = (__bf16*)alloc((size_t)Ddim * 2 * Ddim * 2);  // [512][1024]
    __bf16*   WcTv  = (__bf16*)alloc((size_t)Ddim * Hdim * 2);      // [512][2048]
    __bf16*   WcTa  = (__bf16*)alloc((size_t)Ddim * Hdim * 2);
    __bf16*   g1v   = (__bf16*)alloc((size_t)Mrows * Hdim * 2);
    __bf16*   g1a   = (__bf16*)alloc((size_t)Mrows * Hdim * 2);

    // 1) prep: transposes + dist partials (+x bf16 cast) + bc partials + out-zero
    PrepPtrs pp;
    pp.src[0] = W1v;  pp.dst[0] = WT1v;
    pp.src[1] = W1a;  pp.dst[1] = WT1a;
    pp.src[2] = Wout; pp.dst[2] = WTout;
    pp.xv = x_v; pp.xa = x_a;
    pp.xbf[0] = xbfv; pp.xbf[1] = xbfa;
    pp.pv = pv; pp.pa = pa;
    pp.bm[0] = bmv; pp.bm[1] = bma;
    pp.Wout = Wout; pp.bout = bout;
    pp.bc = bc;
    pp.outz = out;
    prep_kernel<<<dim3(1736), dim3(256), 0, stream>>>(pp);

    // 2) kernelA: gemm1 + WcT product
    APtrs ap;
    ap.xbf[0] = xbfv; ap.xbf[1] = xbfa;
    ap.WT1[0] = WT1v; ap.WT1[1] = WT1a;
    ap.b1[0] = b1v; ap.b1[1] = b1a;
    ap.pd[0] = pv; ap.pd[1] = pa;
    ap.g1[0] = g1v; ap.g1[1] = g1a;
    ap.WTout = WTout;
    ap.Wm[0] = Wmv; ap.Wm[1] = Wma;
    ap.WcT[0] = WcTv; ap.WcT[1] = WcTa;
    kernelA<<<dim3(1024), dim3(256), 0, stream>>>(ap);

    // 3) kernelB: out = sum_z g1[z] @ WcT[z]^T + bc
    BPtrs bp;
    bp.g1[0] = g1v; bp.g1[1] = g1a;
    bp.WcT[0] = WcTv; bp.WcT[1] = WcTa;
    bp.bc = bc; bp.out = out;
    kernelB<<<dim3(512), dim3(256), 0, stream>>>(bp);
}